// Round 6
// baseline (1718.101 us; speedup 1.0000x reference)
//
#include <hip/hip_runtime.h>
#include <hip/hip_cooperative_groups.h>
#include <math.h>

namespace cg = cooperative_groups;

#define NN 50000
#define NE 500000
#define NF 128
#define NO 16
#define SCAN_B 1024
#define NB_SCAN 49   // (NN+SCAN_B-1)/SCAN_B
#define NPART 16
#define EB4 489      // blocks of 1024 edges (4/thread)
#define EB2 977      // blocks of 512 edges (2/thread)

static_assert(NN < 65536, "src must fit u16");

typedef _Float16 f16x8 __attribute__((ext_vector_type(8)));
typedef _Float16 f16x4 __attribute__((ext_vector_type(4)));
typedef float f32x4 __attribute__((ext_vector_type(4)));

union HU { unsigned short u; _Float16 h; };

__device__ inline float rec_w(unsigned int rec) {
    HU cu; cu.u = (unsigned short)(rec >> 16);
    return (float)cu.h;
}

// ---------------- GEMM phase (low-VGPR: two column halves) ----------------

__device__ inline f16x8 afrag_load(const float* X, int row, int k0) {
    const float4* p = (const float4*)(X + (size_t)row * NF + k0);
    float4 a = p[0], b = p[1];
    f16x8 r;
    r[0] = (_Float16)a.x; r[1] = (_Float16)a.y; r[2] = (_Float16)a.z; r[3] = (_Float16)a.w;
    r[4] = (_Float16)b.x; r[5] = (_Float16)b.y; r[6] = (_Float16)b.z; r[7] = (_Float16)b.w;
    return r;
}
__device__ inline f16x8 afrag_load(const _Float16* X, int row, int k0) {
    return *(const f16x8*)(X + (size_t)row * NF + k0);
}

template <typename TA>
__device__ void gemm_phase(const TA* __restrict__ X, const _Float16* __restrict__ WT,
                           const float* __restrict__ dinv, _Float16* __restrict__ Z,
                           int M, char* smem) {
    _Float16 (*ls)[16 * 136] = (_Float16 (*)[16 * 136])smem;
    const int tid  = threadIdx.x;
    const int w    = tid >> 6;
    const int lane = tid & 63;
    const int n16  = lane & 15;
    const int quad = lane >> 4;
    const int nvb  = (M + 63) / 64;
    for (int vb = blockIdx.x; vb < nvb; vb += gridDim.x) {
        const int r0 = vb * 64 + w * 16;
        int arow = r0 + n16; if (arow > M - 1) arow = M - 1;
        f16x8 a[4];
#pragma unroll
        for (int kk = 0; kk < 4; ++kk) a[kk] = afrag_load(X, arow, kk * 32 + quad * 8);
#pragma unroll
        for (int ch = 0; ch < 2; ++ch) {
            f32x4 acc[4];
#pragma unroll
            for (int c = 0; c < 4; ++c) acc[c] = (f32x4){0.f, 0.f, 0.f, 0.f};
#pragma unroll
            for (int kk = 0; kk < 4; ++kk) {
                int k0 = kk * 32 + quad * 8;
#pragma unroll
                for (int c = 0; c < 4; ++c) {
                    f16x8 b = *(const f16x8*)(WT + (size_t)((ch * 4 + c) * 16 + n16) * NF + k0);
                    acc[c] = __builtin_amdgcn_mfma_f32_16x16x32_f16(a[kk], b, acc[c], 0, 0, 0);
                }
            }
#pragma unroll
            for (int reg = 0; reg < 4; ++reg) {
                int lrow = quad * 4 + reg;
                int grow = r0 + lrow; if (grow > M - 1) grow = M - 1;
                float di = dinv[grow];
#pragma unroll
                for (int c = 0; c < 4; ++c)
                    ls[w][lrow * 136 + (ch * 4 + c) * 16 + n16] = (_Float16)(acc[c][reg] * di);
            }
        }
        __syncthreads();
#pragma unroll
        for (int i = 0; i < 4; ++i) {
            int off16 = i * 64 + lane;
            int row = off16 >> 4;
            int col = off16 & 15;
            int grow = r0 + row;
            if (grow < M) {
                f16x8 v = *(const f16x8*)(&ls[w][row * 136 + col * 8]);
                *(f16x8*)(Z + (size_t)grow * NF + col * 8) = v;
            }
        }
        __syncthreads();   // ls reused next vb iteration
    }
}

// ---------------- aggregation phase (R2 masked-uniform body) ----------------
__device__ void agg128_phase(const _Float16* __restrict__ z, const float* __restrict__ dinv,
                             const int* __restrict__ offs_p, const int* __restrict__ bsums2,
                             const unsigned int* __restrict__ erec,
                             const float* __restrict__ bias, _Float16* __restrict__ hout) {
    const int tid  = threadIdx.x;
    const int lane = tid & 63;
    const int half = lane >> 5;      // edge parity
    const int li   = lane & 31;      // feature chunk [li*4, li*4+4)
    for (int vb = blockIdx.x; vb < NN / 4; vb += gridDim.x) {
        int n = __builtin_amdgcn_readfirstlane(vb * 4 + (tid >> 6));

        float acc0 = 0.f, acc1 = 0.f, acc2 = 0.f, acc3 = 0.f;

        int s = offs_p[n] + bsums2[n >> 10];
        int e = (n + 1 < NN) ? offs_p[n + 1] + bsums2[(n + 1) >> 10] : NE;
        for (int base = s; base < e; base += 64) {
            int cnt = e - base; if (cnt > 64) cnt = 64;
            unsigned int rec = 0u;
            if (lane < cnt) rec = __builtin_nontemporal_load(erec + base + lane);
            int   my_s = rec & 0xFFFF;
            float my_w = rec_w(rec);
            int cm1 = cnt - 1;
            for (int k = 0; k < cnt; k += 16) {
                int   sv[8];
                float wv[8];
                f16x4 v[8];
#pragma unroll
                for (int t = 0; t < 8; ++t) {
                    int ei = k + 2 * t + half;
                    int ec = ei < cm1 ? ei : cm1;
                    sv[t] = __shfl(my_s, ec, 64);
                    float wt = __shfl(my_w, ec, 64);
                    wv[t] = (ei < cnt) ? wt : 0.0f;
                }
#pragma unroll
                for (int t = 0; t < 8; ++t)
                    v[t] = *(const f16x4*)(z + ((size_t)sv[t] << 7) + li * 4);
#pragma unroll
                for (int t = 0; t < 8; ++t) {
                    acc0 = fmaf((float)v[t][0], wv[t], acc0);
                    acc1 = fmaf((float)v[t][1], wv[t], acc1);
                    acc2 = fmaf((float)v[t][2], wv[t], acc2);
                    acc3 = fmaf((float)v[t][3], wv[t], acc3);
                }
            }
        }
        acc0 += __shfl_xor(acc0, 32, 64);
        acc1 += __shfl_xor(acc1, 32, 64);
        acc2 += __shfl_xor(acc2, 32, 64);
        acc3 += __shfl_xor(acc3, 32, 64);

        f16x4 sv = *(const f16x4*)(z + ((size_t)n << 7) + li * 4);
        float di = dinv[n];
        float4 bb = *(const float4*)(bias + li * 4);
        float r0 = fmaxf(fmaf(di, (float)sv[0] + acc0, bb.x), 0.0f);
        float r1 = fmaxf(fmaf(di, (float)sv[1] + acc1, bb.y), 0.0f);
        float r2 = fmaxf(fmaf(di, (float)sv[2] + acc2, bb.z), 0.0f);
        float r3 = fmaxf(fmaf(di, (float)sv[3] + acc3, bb.w), 0.0f);
        if (half == 0) {
            f16x4 o;
            o[0] = (_Float16)r0; o[1] = (_Float16)r1;
            o[2] = (_Float16)r2; o[3] = (_Float16)r3;
            __builtin_nontemporal_store(o, (f16x4*)(hout + ((size_t)n << 7) + li * 4));
        }
    }
}

// ---------------- the mega-kernel: whole pipeline, 1 dispatch, 10 grid.syncs ----------------
__global__ __launch_bounds__(256, 5) void k_mega(
    const float* __restrict__ x, const int* __restrict__ esrc,
    const int* __restrict__ edst, const float* __restrict__ ew,
    const float* __restrict__ W1, const float* __restrict__ b1,
    const float* __restrict__ W2, const float* __restrict__ b2,
    const float* __restrict__ W3, const float* __restrict__ b3,
    float* __restrict__ out,
    _Float16* __restrict__ z, _Float16* __restrict__ h, _Float16* __restrict__ z3,
    float* __restrict__ dinv, unsigned int* __restrict__ erec, int* __restrict__ rank,
    int* __restrict__ pcnt, int* __restrict__ offs_p, int* __restrict__ bsums,
    int* __restrict__ bsums2, _Float16* __restrict__ W1T, _Float16* __restrict__ W2T) {
    cg::grid_group grid = cg::this_grid();
    __shared__ __align__(16) char smem[17408];   // overlaid per-phase LDS
    const int tid = threadIdx.x;

    // ---- P0: zero pcnt (replaces hipMemsetAsync) ----
    {
        int gtid = blockIdx.x * 256 + tid;
        int4* p4 = (int4*)pcnt;
        int tot4 = NPART * NN / 4;
        for (int i = gtid; i < tot4; i += gridDim.x * 256) p4[i] = (int4){0, 0, 0, 0};
    }
    grid.sync();

    // ---- P1: count_rank + W1/W2 transpose ----
    for (int b = blockIdx.x; b < EB4 + 64; b += gridDim.x) {
        if (b < EB4 - 1) {
            int part = b & (NPART - 1);
            int e0 = b * 1024 + tid;
            int d0 = edst[e0], d1 = edst[e0 + 256], d2 = edst[e0 + 512], d3 = edst[e0 + 768];
            int r0 = atomicAdd(&pcnt[part * NN + d0], 1);
            int r1 = atomicAdd(&pcnt[part * NN + d1], 1);
            int r2 = atomicAdd(&pcnt[part * NN + d2], 1);
            int r3 = atomicAdd(&pcnt[part * NN + d3], 1);
            rank[e0]       = r0;
            rank[e0 + 256] = r1;
            rank[e0 + 512] = r2;
            rank[e0 + 768] = r3;
        } else if (b == EB4 - 1) {
            int part = b & (NPART - 1);
#pragma unroll
            for (int k = 0; k < 4; ++k) {
                int e = b * 1024 + k * 256 + tid;
                if (e < NE) {
                    int d = edst[e];
                    rank[e] = atomicAdd(&pcnt[part * NN + d], 1);
                }
            }
        } else {
            int idx = (b - EB4) * 256 + tid;   // [0,16384)
            int r = idx >> 7, c = idx & 127;
            W1T[(size_t)c * NF + r] = (_Float16)W1[idx];
            W2T[(size_t)c * NF + r] = (_Float16)W2[idx];
        }
    }
    grid.sync();

    // ---- P2: per-node partition bases (in place) + 1024-node block scans ----
    for (int vb = blockIdx.x; vb < NB_SCAN; vb += gridDim.x) {
        int* sm = (int*)smem;
        int cl[4]; int tot = 0;
        int ibase = vb * SCAN_B + tid * 4;
#pragma unroll
        for (int j = 0; j < 4; ++j) {
            int i = ibase + j; int c = 0;
            if (i < NN) {
                int run = 0;
#pragma unroll
                for (int p = 0; p < NPART; ++p) {
                    int v = pcnt[p * NN + i];
                    pcnt[p * NN + i] = run;
                    run += v;
                }
                c = run;
            }
            cl[j] = tot; tot += c;
        }
        sm[tid] = tot;
        __syncthreads();
        for (int off = 1; off < 256; off <<= 1) {
            int u = (tid >= off) ? sm[tid - off] : 0;
            __syncthreads();
            sm[tid] += u;
            __syncthreads();
        }
        int excl = sm[tid] - tot;
#pragma unroll
        for (int j = 0; j < 4; ++j) {
            int i = ibase + j;
            if (i < NN) offs_p[i] = excl + cl[j];
        }
        if (tid == 255) bsums[vb] = sm[255];
        __syncthreads();
    }
    grid.sync();

    // ---- P3: scatter (prologue: every block scans bsums[49]; block 0 persists) ----
    {
        int* bs_s = (int*)smem;
        if (tid < 64) {
            int v = (tid < NB_SCAN) ? bsums[tid] : 0;
            int orig = v;
#pragma unroll
            for (int off = 1; off < 64; off <<= 1) {
                int u = __shfl_up(v, off, 64);
                if (tid >= off) v += u;
            }
            bs_s[tid] = v - orig;
            if (blockIdx.x == 0 && tid < NB_SCAN) bsums2[tid] = v - orig;
        }
        __syncthreads();
        for (int b = blockIdx.x; b < EB2; b += gridDim.x) {
#pragma unroll
            for (int k = 0; k < 2; ++k) {
                int e = b * 512 + k * 256 + tid;
                if (e < NE) {
                    int part = (e >> 10) & (NPART - 1);
                    int d = edst[e];
                    int pos = offs_p[d] + bs_s[d >> 10] + pcnt[part * NN + d] + rank[e];
                    HU cu; cu.h = (_Float16)ew[e];
                    erec[pos] = (unsigned int)esrc[e] | ((unsigned int)cu.u << 16);
                }
            }
        }
    }
    grid.sync();

    // ---- P4: dinv from CSR (16 lanes per node) ----
    for (int vb = blockIdx.x; vb < (NN + 15) / 16; vb += gridDim.x) {
        int g = tid >> 4, li = tid & 15;
        int n = vb * 16 + g;
        if (n < NN) {
            int s = offs_p[n] + bsums2[n >> 10];
            int e = (n + 1 < NN) ? offs_p[n + 1] + bsums2[(n + 1) >> 10] : NE;
            float d = 0.f;
            for (int j = s + li; j < e; j += 16) d += rec_w(erec[j]);
#pragma unroll
            for (int off = 8; off > 0; off >>= 1) d += __shfl_xor(d, off, 16);
            if (li == 0) dinv[n] = rsqrtf(1.0f + d);
        }
    }
    grid.sync();

    // ---- layer 1 ----
    gemm_phase<float>(x, W1T, dinv, z, NN, smem);
    grid.sync();
    agg128_phase(z, dinv, offs_p, bsums2, erec, b1, h);
    grid.sync();

    // ---- layer 2 ----
    gemm_phase<_Float16>(h, W2T, dinv, z, NN, smem);
    grid.sync();
    agg128_phase(z, dinv, offs_p, bsums2, erec, b2, h);
    grid.sync();

    // ---- gemm16: z3 = dinv ⊙ (h @ W3) ----
    {
        float* Wl = (float*)smem;                  // 2048 floats
        float* Hs = (float*)(smem + NF * NO * 4);  // 16*132 floats
        for (int vb = blockIdx.x; vb < (NN + 15) / 16; vb += gridDim.x) {
            for (int i = tid; i < NF * NO; i += 256) Wl[i] = W3[i];
            int n0 = vb * 16;
            {
                int row = tid >> 4, h8 = tid & 15;
                int gr = n0 + row; if (gr > NN - 1) gr = NN - 1;
                f16x8 v = *(const f16x8*)(h + (size_t)gr * NF + h8 * 8);
                float4 f0 = {(float)v[0], (float)v[1], (float)v[2], (float)v[3]};
                float4 f1 = {(float)v[4], (float)v[5], (float)v[6], (float)v[7]};
                *(float4*)(&Hs[row * 132 + h8 * 8])     = f0;
                *(float4*)(&Hs[row * 132 + h8 * 8 + 4]) = f1;
            }
            __syncthreads();
            int ln = tid >> 4, c = tid & 15;
            float acc = 0.0f;
#pragma unroll 8
            for (int k = 0; k < NF; ++k) acc = fmaf(Hs[ln * 132 + k], Wl[k * NO + c], acc);
            int n = n0 + ln;
            if (n < NN) z3[(size_t)n * NO + c] = (_Float16)(acc * dinv[n]);
            __syncthreads();
        }
    }
    grid.sync();

    // ---- final aggregation + bias + log_softmax ----
    for (int vb = blockIdx.x; vb < NN / 16; vb += gridDim.x) {
        int ln = tid >> 4, c = tid & 15;
        int n = vb * 16 + ln;
        float acc = (float)z3[((size_t)n << 4) + c];
        int s = offs_p[n] + bsums2[n >> 10];
        int e = (n + 1 < NN) ? offs_p[n + 1] + bsums2[(n + 1) >> 10] : NE;
        for (int k = s; k < e; k += 16) {
            float vv[16], ww[16];
#pragma unroll
            for (int t = 0; t < 16; ++t) {
                int idx = k + t;
                int ic = idx < e ? idx : e - 1;
                unsigned int r = erec[ic];
                vv[t] = (float)z3[((size_t)(r & 0xFFFF) << 4) + c];
                ww[t] = (idx < e) ? rec_w(r) : 0.0f;
            }
#pragma unroll
            for (int t = 0; t < 16; ++t) acc = fmaf(vv[t], ww[t], acc);
        }
        acc = fmaf(dinv[n], acc, b3[c]);
        float m = acc;
#pragma unroll
        for (int off = 8; off > 0; off >>= 1) m = fmaxf(m, __shfl_xor(m, off, 16));
        float ex = expf(acc - m);
        float ss = ex;
#pragma unroll
        for (int off = 8; off > 0; off >>= 1) ss += __shfl_xor(ss, off, 16);
        out[(size_t)n * NO + c] = acc - m - logf(ss);
    }
}

// ---------------- launch ----------------

extern "C" void kernel_launch(void* const* d_in, const int* in_sizes, int n_in,
                              void* d_out, int out_size, void* d_ws, size_t ws_size,
                              hipStream_t stream) {
    const float* x   = (const float*)d_in[0];
    const int*   esrc= (const int*)  d_in[1];
    const int*   edst= (const int*)  d_in[2];
    const float* ew  = (const float*)d_in[3];
    const float* W1  = (const float*)d_in[4];
    const float* b1  = (const float*)d_in[5];
    const float* W2  = (const float*)d_in[6];
    const float* b2  = (const float*)d_in[7];
    const float* W3  = (const float*)d_in[8];
    const float* b3  = (const float*)d_in[9];
    float* out = (float*)d_out;

    // workspace carve
    char* p = (char*)d_ws;
    _Float16* z   = (_Float16*)p; p += (size_t)NN * NF * 2;   // 12.8 MB
    _Float16* h   = (_Float16*)p; p += (size_t)NN * NF * 2;   // 12.8 MB
    _Float16* z3  = (_Float16*)p; p += (size_t)NN * NO * 2;   // 1.6 MB
    float* dinv   = (float*)p; p += (size_t)NN * 4;
    unsigned int* erec = (unsigned int*)p; p += (size_t)NE * 4;
    int*   rank   = (int*)p;   p += (size_t)NE * 4;
    int*   pcnt   = (int*)p;   p += (size_t)NPART * NN * 4;   // 3.2 MB (zeroed in P0)
    int*   offs_p = (int*)p;   p += (size_t)(NN + 16) * 4;
    int*   bsums  = (int*)p;   p += 256;
    int*   bsums2 = (int*)p;   p += 256;
    _Float16* W1T = (_Float16*)p; p += (size_t)NF * NF * 2;
    _Float16* W2T = (_Float16*)p; p += (size_t)NF * NF * 2;

    void* kargs[] = {&x, &esrc, &edst, &ew, &W1, &b1, &W2, &b2, &W3, &b3, &out,
                     &z, &h, &z3, &dinv, &erec, &rank, &pcnt, &offs_p, &bsums,
                     &bsums2, &W1T, &W2T};

    // one dispatch for the whole pipeline; fall back to smaller co-resident grids
    hipError_t err = hipLaunchCooperativeKernel((void*)k_mega, dim3(1280), dim3(256),
                                                kargs, 0, stream);
    if (err != hipSuccess)
        err = hipLaunchCooperativeKernel((void*)k_mega, dim3(1024), dim3(256),
                                         kargs, 0, stream);
    if (err != hipSuccess)
        hipLaunchCooperativeKernel((void*)k_mega, dim3(512), dim3(256),
                                   kargs, 0, stream);
}

// Round 7
// 240.082 us; speedup vs baseline: 7.1563x; 7.1563x over previous
//
#include <hip/hip_runtime.h>
#include <math.h>

#define NN 50000
#define NE 500000
#define NF 128
#define NO 16
#define SCAN_B 1024
#define NB_SCAN 49   // (NN+SCAN_B-1)/SCAN_B
#define NPART 16
#define EB4 489      // blocks of 1024 edges (4/thread)
#define EB2 977      // blocks of 512 edges (2/thread)

static_assert(NN < 65536, "src must fit u16");

typedef _Float16 f16x8 __attribute__((ext_vector_type(8)));
typedef _Float16 f16x4 __attribute__((ext_vector_type(4)));
typedef float f32x4 __attribute__((ext_vector_type(4)));

union HU { unsigned short u; _Float16 h; };

__device__ inline float rec_w(unsigned int rec) {
    HU cu; cu.u = (unsigned short)(rec >> 16);
    return (float)cu.h;
}

// ---------------- graph preprocessing (atomic-light CSR build) ----------------
// Edge partition for rank disambiguation: part(e) = (e >> 10) & 15.

// pass 1: per-edge rank within (partition, dst) via returning atomics, 4 edges
// per thread for memory-level parallelism; spare blocks transpose W1/W2 to fp16.
__global__ __launch_bounds__(256) void k_count_rank(const int* __restrict__ dst,
                                                    int* __restrict__ pcnt,
                                                    int* __restrict__ rank, int E,
                                                    const float* __restrict__ W1,
                                                    const float* __restrict__ W2,
                                                    _Float16* __restrict__ W1T,
                                                    _Float16* __restrict__ W2T) {
    int b = blockIdx.x;
    if (b < EB4 - 1) {
        int part = b & (NPART - 1);
        int e0 = b * 1024 + threadIdx.x;
        int d0 = dst[e0], d1 = dst[e0 + 256], d2 = dst[e0 + 512], d3 = dst[e0 + 768];
        int r0 = atomicAdd(&pcnt[part * NN + d0], 1);
        int r1 = atomicAdd(&pcnt[part * NN + d1], 1);
        int r2 = atomicAdd(&pcnt[part * NN + d2], 1);
        int r3 = atomicAdd(&pcnt[part * NN + d3], 1);
        rank[e0]       = r0;
        rank[e0 + 256] = r1;
        rank[e0 + 512] = r2;
        rank[e0 + 768] = r3;
    } else if (b == EB4 - 1) {
        int part = b & (NPART - 1);
#pragma unroll
        for (int k = 0; k < 4; ++k) {
            int e = b * 1024 + k * 256 + threadIdx.x;
            if (e < E) {
                int d = dst[e];
                rank[e] = atomicAdd(&pcnt[part * NN + d], 1);
            }
        }
    } else {
        int idx = (b - EB4) * 256 + threadIdx.x;   // [0,16384)
        int r = idx >> 7, c = idx & 127;
        W1T[(size_t)c * NF + r] = (_Float16)W1[idx];
        W2T[(size_t)c * NF + r] = (_Float16)W2[idx];
    }
}

// pass 2: per-node partition bases (in place) + block scan of totals + fused
// 49-block top-level scan via last-block pattern (agent-scope atomics).
__global__ void k_scan1f(int* __restrict__ pcnt, int* __restrict__ offs_p,
                         int* __restrict__ bsums, int* __restrict__ done) {
    __shared__ int sm[SCAN_B];
    __shared__ int isLast;
    int t = threadIdx.x;
    int i = blockIdx.x * SCAN_B + t;
    int c = 0;
    if (i < NN) {
        int run = 0;
#pragma unroll
        for (int p = 0; p < NPART; ++p) {
            int v = pcnt[p * NN + i];
            pcnt[p * NN + i] = run;
            run += v;
        }
        c = run;
    }
    sm[t] = c;
    __syncthreads();
    for (int off = 1; off < SCAN_B; off <<= 1) {
        int x = (t >= off) ? sm[t - off] : 0;
        __syncthreads();
        sm[t] += x;
        __syncthreads();
    }
    if (i < NN) offs_p[i] = sm[t] - c;
    if (t == SCAN_B - 1) {
        __hip_atomic_store(&bsums[blockIdx.x], sm[t], __ATOMIC_RELEASE,
                           __HIP_MEMORY_SCOPE_AGENT);
        int old = __hip_atomic_fetch_add(done, 1, __ATOMIC_ACQ_REL,
                                         __HIP_MEMORY_SCOPE_AGENT);
        isLast = (old == (int)gridDim.x - 1) ? 1 : 0;
    }
    __syncthreads();
    if (isLast && t < 64) {
        int v = (t < NB_SCAN) ? __hip_atomic_load(&bsums[t], __ATOMIC_ACQUIRE,
                                                  __HIP_MEMORY_SCOPE_AGENT) : 0;
        int orig = v;
#pragma unroll
        for (int off = 1; off < 64; off <<= 1) {
            int u = __shfl_up(v, off, 64);
            if (t >= off) v += u;
        }
        if (t < NB_SCAN)
            __hip_atomic_store(&bsums[t], v - orig, __ATOMIC_RELEASE,
                               __HIP_MEMORY_SCOPE_AGENT);
    }
}

// pass 3: atomic-free scatter of packed 4B {src:u16, ew:fp16} records, 2/thread
__global__ __launch_bounds__(256) void k_scatter(const int* __restrict__ src,
                                                 const int* __restrict__ dst,
                                                 const float* __restrict__ ew,
                                                 const int* __restrict__ pcnt,
                                                 const int* __restrict__ rank,
                                                 const int* __restrict__ offs_p,
                                                 const int* __restrict__ bsums,
                                                 unsigned int* __restrict__ erec, int E) {
    int b = blockIdx.x;
#pragma unroll
    for (int k = 0; k < 2; ++k) {
        int e = b * 512 + k * 256 + threadIdx.x;
        if (e < E) {
            int part = (e >> 10) & (NPART - 1);
            int d = dst[e];
            int pos = offs_p[d] + bsums[d >> 10] + pcnt[part * NN + d] + rank[e];
            HU cu; cu.h = (_Float16)ew[e];
            erec[pos] = (unsigned int)src[e] | ((unsigned int)cu.u << 16);
        }
    }
}

// pass 4: deg from CSR -> dinv; 16 lanes cooperate per node
__global__ __launch_bounds__(256) void k_dinv_csr(const unsigned int* __restrict__ erec,
                                                  const int* __restrict__ offs_p,
                                                  const int* __restrict__ bsums,
                                                  float* __restrict__ dinv) {
    int tid = threadIdx.x;
    int g = tid >> 4, li = tid & 15;
    int n = blockIdx.x * 16 + g;
    if (n >= NN) return;
    int s = offs_p[n] + bsums[n >> 10];
    int e = (n + 1 < NN) ? offs_p[n + 1] + bsums[(n + 1) >> 10] : NE;
    float d = 0.f;
    for (int j = s + li; j < e; j += 16) d += rec_w(erec[j]);
#pragma unroll
    for (int off = 8; off > 0; off >>= 1) d += __shfl_xor(d, off, 16);
    if (li == 0) dinv[n] = rsqrtf(1.0f + d);
}

// ---------------- MFMA GEMM: Z[M,128](fp16, row-major) = dinv ⊙ (X @ W) ----------------

__device__ inline f16x8 afrag_load(const float* X, int row, int k0) {
    const float4* p = (const float4*)(X + (size_t)row * NF + k0);
    float4 a = p[0], b = p[1];
    f16x8 r;
    r[0] = (_Float16)a.x; r[1] = (_Float16)a.y; r[2] = (_Float16)a.z; r[3] = (_Float16)a.w;
    r[4] = (_Float16)b.x; r[5] = (_Float16)b.y; r[6] = (_Float16)b.z; r[7] = (_Float16)b.w;
    return r;
}
__device__ inline f16x8 afrag_load(const _Float16* X, int row, int k0) {
    return *(const f16x8*)(X + (size_t)row * NF + k0);
}

template <typename TA>
__global__ __launch_bounds__(256) void k_gemm_mfma(const TA* __restrict__ X,
                                                   const _Float16* __restrict__ WT,
                                                   const float* __restrict__ dinv,
                                                   _Float16* __restrict__ Z, int M) {
    __shared__ _Float16 ls[4][16 * 136];      // padded stride 136 halves
    const int tid  = threadIdx.x;
    const int w    = tid >> 6;
    const int lane = tid & 63;
    const int n16  = lane & 15;
    const int quad = lane >> 4;
    const int r0   = blockIdx.x * 64 + w * 16;

    int arow = r0 + n16; if (arow > M - 1) arow = M - 1;

    f32x4 acc[8];
#pragma unroll
    for (int c = 0; c < 8; ++c) acc[c] = (f32x4){0.f, 0.f, 0.f, 0.f};

#pragma unroll
    for (int kk = 0; kk < 4; ++kk) {
        int k0 = kk * 32 + quad * 8;
        f16x8 a = afrag_load(X, arow, k0);
#pragma unroll
        for (int c = 0; c < 8; ++c) {
            f16x8 b = *(const f16x8*)(WT + (size_t)(c * 16 + n16) * NF + k0);
            acc[c] = __builtin_amdgcn_mfma_f32_16x16x32_f16(a, b, acc[c], 0, 0, 0);
        }
    }

#pragma unroll
    for (int reg = 0; reg < 4; ++reg) {
        int lrow = quad * 4 + reg;
        int grow = r0 + lrow; if (grow > M - 1) grow = M - 1;
        float di = dinv[grow];
#pragma unroll
        for (int c = 0; c < 8; ++c)
            ls[w][lrow * 136 + c * 16 + n16] = (_Float16)(acc[c][reg] * di);
    }
    __syncthreads();
#pragma unroll
    for (int i = 0; i < 4; ++i) {
        int off16 = i * 64 + lane;
        int row = off16 >> 4;
        int col = off16 & 15;
        int grow = r0 + row;
        if (grow < M) {
            f16x8 v = *(const f16x8*)(&ls[w][row * 136 + col * 8]);
            *(f16x8*)(Z + (size_t)grow * NF + col * 8) = v;
        }
    }
}

// ---------------- aggregation, 128-wide, 4-edge/1KB gather instructions ----------------
// 16 lanes cover a full 256B z-row via f16x8 (16B/lane, coalescing sweet spot);
// the 4 16-lane quads process 4 edges per vector-memory instruction (vs 2 at
// f16x4), halving gather-instruction and shfl counts for the same bytes.
__global__ __launch_bounds__(256) void k_agg128h(const _Float16* __restrict__ z,
                                                 const float* __restrict__ dinv,
                                                 const int* __restrict__ offs_p,
                                                 const int* __restrict__ bsums,
                                                 const unsigned int* __restrict__ erec,
                                                 const float* __restrict__ bias,
                                                 _Float16* __restrict__ hout, int relu) {
    const int tid  = threadIdx.x;
    const int lane = tid & 63;
    const int q    = lane >> 4;      // edge slot within a gather instruction
    const int li   = lane & 15;      // feature chunk [li*8, li*8+8)
    int n = __builtin_amdgcn_readfirstlane(blockIdx.x * 4 + (tid >> 6));

    float acc[8];
#pragma unroll
    for (int j = 0; j < 8; ++j) acc[j] = 0.f;

    int s = offs_p[n] + bsums[n >> 10];
    int e = (n + 1 < NN) ? offs_p[n + 1] + bsums[(n + 1) >> 10] : NE;
    for (int base = s; base < e; base += 64) {
        int cnt = e - base; if (cnt > 64) cnt = 64;
        unsigned int rec = 0u;
        if (lane < cnt) rec = erec[base + lane];
        int   my_s = rec & 0xFFFF;
        float my_w = rec_w(rec);
        int cm1 = cnt - 1;
        for (int k = 0; k < cnt; k += 16) {
            int   sv[4];
            float wv[4];
            f16x8 v[4];
#pragma unroll
            for (int t = 0; t < 4; ++t) {
                int ei = k + 4 * t + q;
                int ec = ei < cm1 ? ei : cm1;
                sv[t] = __shfl(my_s, ec, 64);
                float wt = __shfl(my_w, ec, 64);
                wv[t] = (ei < cnt) ? wt : 0.0f;
            }
#pragma unroll
            for (int t = 0; t < 4; ++t)
                v[t] = *(const f16x8*)(z + ((size_t)sv[t] << 7) + li * 8);
#pragma unroll
            for (int t = 0; t < 4; ++t) {
#pragma unroll
                for (int j = 0; j < 8; ++j)
                    acc[j] = fmaf((float)v[t][j], wv[t], acc[j]);
            }
        }
    }
#pragma unroll
    for (int j = 0; j < 8; ++j) {
        acc[j] += __shfl_xor(acc[j], 32, 64);
        acc[j] += __shfl_xor(acc[j], 16, 64);
    }

    f16x8 sv8 = *(const f16x8*)(z + ((size_t)n << 7) + li * 8);
    float di = dinv[n];
    float4 bb0 = *(const float4*)(bias + li * 8);
    float4 bb1 = *(const float4*)(bias + li * 8 + 4);
    float r[8];
    r[0] = fmaf(di, (float)sv8[0] + acc[0], bb0.x);
    r[1] = fmaf(di, (float)sv8[1] + acc[1], bb0.y);
    r[2] = fmaf(di, (float)sv8[2] + acc[2], bb0.z);
    r[3] = fmaf(di, (float)sv8[3] + acc[3], bb0.w);
    r[4] = fmaf(di, (float)sv8[4] + acc[4], bb1.x);
    r[5] = fmaf(di, (float)sv8[5] + acc[5], bb1.y);
    r[6] = fmaf(di, (float)sv8[6] + acc[6], bb1.z);
    r[7] = fmaf(di, (float)sv8[7] + acc[7], bb1.w);
    if (relu) {
#pragma unroll
        for (int j = 0; j < 8; ++j) r[j] = fmaxf(r[j], 0.0f);
    }
    if (q == 0) {
        f16x8 o;
#pragma unroll
        for (int j = 0; j < 8; ++j) o[j] = (_Float16)r[j];
        __builtin_nontemporal_store(o, (f16x8*)(hout + ((size_t)n << 7) + li * 8));
    }
}

// ---------------- GEMM: Z3[M,16](fp16) = dinv ⊙ (H[M,128](fp16) @ W3[128,16]) ----------------
__global__ __launch_bounds__(256) void k_gemm16(const _Float16* __restrict__ H,
                                                const float* __restrict__ W3,
                                                const float* __restrict__ dinv,
                                                _Float16* __restrict__ Z3, int M) {
    __shared__ float Wl[NF * NO];
    __shared__ float Hs[16 * 132];
    int tid = threadIdx.x;
    for (int i = tid; i < NF * NO; i += 256) Wl[i] = W3[i];
    int n0 = blockIdx.x * 16;
    {
        int row = tid >> 4, h8 = tid & 15;
        int gr = n0 + row; if (gr > M - 1) gr = M - 1;
        f16x8 v = *(const f16x8*)(H + (size_t)gr * NF + h8 * 8);
        float4 f0 = {(float)v[0], (float)v[1], (float)v[2], (float)v[3]};
        float4 f1 = {(float)v[4], (float)v[5], (float)v[6], (float)v[7]};
        *(float4*)(&Hs[row * 132 + h8 * 8])     = f0;
        *(float4*)(&Hs[row * 132 + h8 * 8 + 4]) = f1;
    }
    __syncthreads();
    int ln = tid >> 4, c = tid & 15;
    float acc = 0.0f;
#pragma unroll 8
    for (int k = 0; k < NF; ++k) acc = fmaf(Hs[ln * 132 + k], Wl[k * NO + c], acc);
    int n = n0 + ln;
    if (n < M) Z3[(size_t)n * NO + c] = (_Float16)(acc * dinv[n]);
}

// ---------------- final aggregation (16-wide) + bias + log_softmax ----------------
__global__ __launch_bounds__(256) void k_agg16_ls(const _Float16* __restrict__ z3,
                                                  const float* __restrict__ dinv,
                                                  const int* __restrict__ offs_p,
                                                  const int* __restrict__ bsums,
                                                  const unsigned int* __restrict__ erec,
                                                  const float* __restrict__ bias,
                                                  float* __restrict__ out) {
    int tid = threadIdx.x;
    int ln = tid >> 4, c = tid & 15;
    int n = blockIdx.x * 16 + ln;
    float acc = (float)z3[((size_t)n << 4) + c];
    int s = offs_p[n] + bsums[n >> 10];
    int e = (n + 1 < NN) ? offs_p[n + 1] + bsums[(n + 1) >> 10] : NE;
    for (int k = s; k < e; k += 16) {
        float vv[16], ww[16];
#pragma unroll
        for (int t = 0; t < 16; ++t) {
            int idx = k + t;
            int ic = idx < e ? idx : e - 1;
            unsigned int r = erec[ic];
            vv[t] = (float)z3[((size_t)(r & 0xFFFF) << 4) + c];
            ww[t] = (idx < e) ? rec_w(r) : 0.0f;
        }
#pragma unroll
        for (int t = 0; t < 16; ++t) acc = fmaf(vv[t], ww[t], acc);
    }
    acc = fmaf(dinv[n], acc, bias[c]);
    float m = acc;
#pragma unroll
    for (int off = 8; off > 0; off >>= 1) m = fmaxf(m, __shfl_xor(m, off, 16));
    float ex = expf(acc - m);
    float ss = ex;
#pragma unroll
    for (int off = 8; off > 0; off >>= 1) ss += __shfl_xor(ss, off, 16);
    out[(size_t)n * NO + c] = acc - m - logf(ss);
}

// ---------------- launch ----------------

extern "C" void kernel_launch(void* const* d_in, const int* in_sizes, int n_in,
                              void* d_out, int out_size, void* d_ws, size_t ws_size,
                              hipStream_t stream) {
    const float* x   = (const float*)d_in[0];
    const int*   esrc= (const int*)  d_in[1];
    const int*   edst= (const int*)  d_in[2];
    const float* ew  = (const float*)d_in[3];
    const float* W1  = (const float*)d_in[4];
    const float* b1  = (const float*)d_in[5];
    const float* W2  = (const float*)d_in[6];
    const float* b2  = (const float*)d_in[7];
    const float* W3  = (const float*)d_in[8];
    const float* b3  = (const float*)d_in[9];
    float* out = (float*)d_out;

    // workspace carve
    char* p = (char*)d_ws;
    _Float16* z   = (_Float16*)p; p += (size_t)NN * NF * 2;   // 12.8 MB
    _Float16* h   = (_Float16*)p; p += (size_t)NN * NF * 2;   // 12.8 MB
    _Float16* z3  = (_Float16*)p; p += (size_t)NN * NO * 2;   // 1.6 MB
    float* dinv   = (float*)p; p += (size_t)NN * 4;
    unsigned int* erec = (unsigned int*)p; p += (size_t)NE * 4;
    int*   rank   = (int*)p;   p += (size_t)NE * 4;
    // zeroed region: pcnt | done (single memset)
    int*   pcnt   = (int*)p;   p += (size_t)NPART * NN * 4;   // 3.2 MB
    int*   done   = (int*)p;   p += 64;
    int*   offs_p = (int*)p;   p += (size_t)(NN + 1) * 4;
    int*   bsums  = (int*)p;   p += 256;
    _Float16* W1T = (_Float16*)p; p += (size_t)NF * NF * 2;
    _Float16* W2T = (_Float16*)p; p += (size_t)NF * NF * 2;

    hipMemsetAsync(pcnt, 0, (size_t)NPART * NN * 4 + 64, stream);

    k_count_rank<<<EB4 + 64, 256, 0, stream>>>(edst, pcnt, rank, NE, W1, W2, W1T, W2T);
    k_scan1f<<<NB_SCAN, SCAN_B, 0, stream>>>(pcnt, offs_p, bsums, done);
    k_scatter<<<EB2, 256, 0, stream>>>(esrc, edst, ew, pcnt, rank, offs_p, bsums, erec, NE);
    k_dinv_csr<<<(NN + 15) / 16, 256, 0, stream>>>(erec, offs_p, bsums, dinv);

    // layer 1
    k_gemm_mfma<float><<<(NN + 63) / 64, 256, 0, stream>>>(x, W1T, dinv, z, NN);
    k_agg128h<<<NN / 4, 256, 0, stream>>>(z, dinv, offs_p, bsums, erec, b1, h, 1);
    // layer 2
    k_gemm_mfma<_Float16><<<(NN + 63) / 64, 256, 0, stream>>>(h, W2T, dinv, z, NN);
    k_agg128h<<<NN / 4, 256, 0, stream>>>(z, dinv, offs_p, bsums, erec, b2, h, 1);
    // layer 3
    k_gemm16<<<(NN + 15) / 16, 256, 0, stream>>>(h, W3, dinv, z3, NN);
    k_agg16_ls<<<NN / 16, 256, 0, stream>>>(z3, dinv, offs_p, bsums, erec, b3, out);
}